// Round 3
// baseline (247.841 us; speedup 1.0000x reference)
//
#include <hip/hip_runtime.h>

#define NPT    16384
#define TOTP   32768          // B*N
#define FD     128
#define NROWS  (TOTP*4)       // 131072
#define NTILES (NROWS/32)     // 4096 step tiles (8 points x 4 nbrs)
#define FTILES (TOTP/32)      // 1024 fproj tiles (32 points)

typedef unsigned short u16;
typedef __attribute__((ext_vector_type(8))) short bf16x8;
typedef __attribute__((ext_vector_type(4))) float f32x4;

__device__ __forceinline__ float bf2f(u16 u) {
    union { unsigned int i; float f; } v; v.i = ((unsigned int)u) << 16; return v.f;
}
__device__ __forceinline__ u16 f2bf(float f) {
    union { float f; unsigned int i; } v; v.f = f;
    unsigned int u = v.i;
    u = u + 0x7FFFu + ((u >> 16) & 1u);   // RNE
    return (u16)(u >> 16);
}
// 32x128 bf16 tile, row stride 256B, G4 XOR swizzle (conflict-free b128 col reads)
__device__ __forceinline__ int swz(int row, int colbyte) {
    return row*256 + (colbyte ^ ((row & 7) << 4));
}

// ---------------------------------------------------------------------------
// fproj[p][j] = b0[j] + feat[p] @ W0[3:]   (feat = relu(pcl@Wf1+bf1)@Wf2+bf2)
// 4 waves col-split (32 cols each), weights register-resident, 2 barriers/tile.
// ---------------------------------------------------------------------------
__global__ __launch_bounds__(256, 3) void fproj_mfma(
    const float* __restrict__ pcl, const float* __restrict__ Wf1,
    const float* __restrict__ bf1, const float* __restrict__ Wf2,
    const float* __restrict__ bf2, const float* __restrict__ W0,
    const float* __restrict__ b0, u16* __restrict__ fproj)
{
    __shared__ __align__(16) char hA[8192];
    __shared__ __align__(16) char hB[8192];
    const int tid = threadIdx.x, wid = tid >> 6, l = tid & 63;
    const int l15 = l & 15, l4 = l >> 4;
    const int colb = wid * 32;

    bf16x8 wfA[2][4], wfB[2][4];   // Wf2 / W0[3:] B-frags for this wave's cols
    #pragma unroll
    for (int ntg = 0; ntg < 2; ++ntg)
        #pragma unroll
        for (int kk = 0; kk < 4; ++kk) {
            bf16x8 fa, fb;
            #pragma unroll
            for (int e = 0; e < 8; ++e) {
                int k = kk*32 + l4*8 + e;
                int n = colb + ntg*16 + l15;
                fa[e] = (short)f2bf(Wf2[k*FD + n]);
                fb[e] = (short)f2bf(W0[(3+k)*FD + n]);
            }
            wfA[ntg][kk] = fa; wfB[ntg][kk] = fb;
        }
    float wf1c[3][2], bf1v[2], bf2v[2], b0v[2];
    #pragma unroll
    for (int ntg = 0; ntg < 2; ++ntg) {
        int col = colb + ntg*16 + l15;
        wf1c[0][ntg] = Wf1[0*FD+col];
        wf1c[1][ntg] = Wf1[1*FD+col];
        wf1c[2][ntg] = Wf1[2*FD+col];
        bf1v[ntg] = bf1[col]; bf2v[ntg] = bf2[col]; b0v[ntg] = b0[col];
    }

    for (int tile = blockIdx.x; tile < FTILES; tile += gridDim.x) {
        const int pt0 = tile * 32;
        // ---- t = relu(pcl@Wf1+bf1) -> hA ----
        #pragma unroll
        for (int rt = 0; rt < 2; ++rt)
            #pragma unroll
            for (int reg = 0; reg < 4; ++reg) {
                int row = rt*16 + l4*4 + reg;
                int p = pt0 + row;
                float px = pcl[p*3+0], py = pcl[p*3+1], pz = pcl[p*3+2];
                #pragma unroll
                for (int ntg = 0; ntg < 2; ++ntg) {
                    float t = bf1v[ntg] + px*wf1c[0][ntg] + py*wf1c[1][ntg] + pz*wf1c[2][ntg];
                    t = fmaxf(t, 0.f);
                    int col = colb + ntg*16 + l15;
                    *(u16*)(hA + swz(row, col*2)) = f2bf(t);
                }
            }
        __syncthreads();
        // ---- feat = t @ Wf2 + bf2 -> hB (no relu) ----
        {
            bf16x8 a[2][4];
            #pragma unroll
            for (int rt = 0; rt < 2; ++rt)
                #pragma unroll
                for (int kk = 0; kk < 4; ++kk)
                    a[rt][kk] = *(const bf16x8*)(hA + swz(rt*16 + l15, kk*64 + l4*16));
            #pragma unroll
            for (int ntg = 0; ntg < 2; ++ntg) {
                f32x4 acc0 = {bf2v[ntg],bf2v[ntg],bf2v[ntg],bf2v[ntg]};
                f32x4 acc1 = acc0;
                #pragma unroll
                for (int kk = 0; kk < 4; ++kk) {
                    acc0 = __builtin_amdgcn_mfma_f32_16x16x32_bf16(a[0][kk], wfA[ntg][kk], acc0, 0,0,0);
                    acc1 = __builtin_amdgcn_mfma_f32_16x16x32_bf16(a[1][kk], wfA[ntg][kk], acc1, 0,0,0);
                }
                int col = colb + ntg*16 + l15;
                #pragma unroll
                for (int reg = 0; reg < 4; ++reg) {
                    *(u16*)(hB + swz(l4*4+reg,      col*2)) = f2bf(acc0[reg]);
                    *(u16*)(hB + swz(16+l4*4+reg,   col*2)) = f2bf(acc1[reg]);
                }
            }
        }
        __syncthreads();
        // ---- fproj = feat @ W0[3:] + b0 -> global ----
        {
            bf16x8 a[2][4];
            #pragma unroll
            for (int rt = 0; rt < 2; ++rt)
                #pragma unroll
                for (int kk = 0; kk < 4; ++kk)
                    a[rt][kk] = *(const bf16x8*)(hB + swz(rt*16 + l15, kk*64 + l4*16));
            #pragma unroll
            for (int ntg = 0; ntg < 2; ++ntg) {
                f32x4 acc0 = {b0v[ntg],b0v[ntg],b0v[ntg],b0v[ntg]};
                f32x4 acc1 = acc0;
                #pragma unroll
                for (int kk = 0; kk < 4; ++kk) {
                    acc0 = __builtin_amdgcn_mfma_f32_16x16x32_bf16(a[0][kk], wfB[ntg][kk], acc0, 0,0,0);
                    acc1 = __builtin_amdgcn_mfma_f32_16x16x32_bf16(a[1][kk], wfB[ntg][kk], acc1, 0,0,0);
                }
                int col = colb + ntg*16 + l15;
                #pragma unroll
                for (int reg = 0; reg < 4; ++reg) {
                    fproj[(size_t)(pt0 + l4*4+reg)*FD + col]      = f2bf(acc0[reg]);
                    fproj[(size_t)(pt0 + 16 + l4*4+reg)*FD + col] = f2bf(acc1[reg]);
                }
            }
        }
        __syncthreads();
    }
}

// ---------------------------------------------------------------------------
// One denoise step: dst (pre-copied from cur) += s * scatter(grad).
// Tile = 32 rows (8 points x 4 nbrs); 4 waves col-split; Wb in registers;
// epilogue grad via padded-Wo MFMA (waves 0,1) -> direct atomics.
// ---------------------------------------------------------------------------
__global__ __launch_bounds__(256, 3) void step_mfma(
    const float* __restrict__ cur, const float* __restrict__ noisy,
    const u16* __restrict__ fproj, const float* __restrict__ W0,
    const float* __restrict__ Wb, const float* __restrict__ bb,
    const float* __restrict__ Wo, const float* __restrict__ bo,
    float* __restrict__ dst, float s)
{
    __shared__ __align__(16) char hA[8192];
    __shared__ __align__(16) char hB[8192];
    __shared__ __align__(16) char hC[8192];
    const int tid = threadIdx.x, wid = tid >> 6, l = tid & 63;
    const int l15 = l & 15, l4 = l >> 4;
    const int colb = wid * 32;

    bf16x8 wfrag[2][2][4];   // [layer][ntg][kk]
    #pragma unroll
    for (int layer = 0; layer < 2; ++layer)
        #pragma unroll
        for (int ntg = 0; ntg < 2; ++ntg)
            #pragma unroll
            for (int kk = 0; kk < 4; ++kk) {
                bf16x8 f;
                #pragma unroll
                for (int e = 0; e < 8; ++e) {
                    int k = kk*32 + l4*8 + e;
                    int n = colb + ntg*16 + l15;
                    f[e] = (short)f2bf(Wb[layer*FD*FD + k*FD + n]);
                }
                wfrag[layer][ntg][kk] = f;
            }
    bf16x8 wofrag[4];        // Wo padded 128x16 (cols>=3 zero)
    #pragma unroll
    for (int kk = 0; kk < 4; ++kk) {
        bf16x8 f;
        #pragma unroll
        for (int e = 0; e < 8; ++e) {
            int k = kk*32 + l4*8 + e;
            f[e] = (short)(l15 < 3 ? f2bf(Wo[k*3 + l15]) : 0);
        }
        wofrag[kk] = f;
    }
    float w0c[3][2], bbv[2][2];
    #pragma unroll
    for (int ntg = 0; ntg < 2; ++ntg) {
        int col = colb + ntg*16 + l15;
        w0c[0][ntg] = W0[0*FD+col];
        w0c[1][ntg] = W0[1*FD+col];
        w0c[2][ntg] = W0[2*FD+col];
        bbv[0][ntg] = bb[col]; bbv[1][ntg] = bb[FD+col];
    }
    const float bol = (l15 < 3) ? bo[l15] : 0.f;

    for (int tile = blockIdx.x; tile < NTILES; tile += gridDim.x) {
        const int pt0 = tile * 8;
        float hc[2][2][4];   // [rt][ntg][reg] residual, C-layout
        // ---- layer0: h0 = relu(cent@W0[:3] + fproj) -> hA ----
        #pragma unroll
        for (int rt = 0; rt < 2; ++rt) {
            int p = pt0 + rt*4 + l4;
            int b = p >> 14, n = p & (NPT-1);
            float nx = noisy[p*3+0], ny = noisy[p*3+1], nz = noisy[p*3+2];
            float cx[4], cy[4], cz[4];
            #pragma unroll
            for (int k = 0; k < 4; ++k) {
                int nb = n + k - 2;
                nb = nb < 0 ? 0 : (nb > NPT-1 ? NPT-1 : nb);
                int pn = (b << 14) + nb;
                cx[k] = cur[pn*3+0] - nx;
                cy[k] = cur[pn*3+1] - ny;
                cz[k] = cur[pn*3+2] - nz;
            }
            #pragma unroll
            for (int ntg = 0; ntg < 2; ++ntg) {
                int col = colb + ntg*16 + l15;
                float fp = bf2f(fproj[(size_t)p*FD + col]);
                #pragma unroll
                for (int reg = 0; reg < 4; ++reg) {
                    float u = fp + cx[reg]*w0c[0][ntg] + cy[reg]*w0c[1][ntg] + cz[reg]*w0c[2][ntg];
                    u = fmaxf(u, 0.f);
                    hc[rt][ntg][reg] = u;
                    *(u16*)(hA + swz(rt*16 + l4*4 + reg, col*2)) = f2bf(u);
                }
            }
        }
        __syncthreads();
        // ---- layer1: h += relu(h@Wb0+bb0) -> hB ----
        {
            bf16x8 a[2][4];
            #pragma unroll
            for (int rt = 0; rt < 2; ++rt)
                #pragma unroll
                for (int kk = 0; kk < 4; ++kk)
                    a[rt][kk] = *(const bf16x8*)(hA + swz(rt*16 + l15, kk*64 + l4*16));
            #pragma unroll
            for (int ntg = 0; ntg < 2; ++ntg) {
                f32x4 acc0 = {bbv[0][ntg],bbv[0][ntg],bbv[0][ntg],bbv[0][ntg]};
                f32x4 acc1 = acc0;
                #pragma unroll
                for (int kk = 0; kk < 4; ++kk) {
                    acc0 = __builtin_amdgcn_mfma_f32_16x16x32_bf16(a[0][kk], wfrag[0][ntg][kk], acc0, 0,0,0);
                    acc1 = __builtin_amdgcn_mfma_f32_16x16x32_bf16(a[1][kk], wfrag[0][ntg][kk], acc1, 0,0,0);
                }
                int col = colb + ntg*16 + l15;
                #pragma unroll
                for (int reg = 0; reg < 4; ++reg) {
                    hc[0][ntg][reg] += fmaxf(acc0[reg], 0.f);
                    hc[1][ntg][reg] += fmaxf(acc1[reg], 0.f);
                    *(u16*)(hB + swz(l4*4+reg,    col*2)) = f2bf(hc[0][ntg][reg]);
                    *(u16*)(hB + swz(16+l4*4+reg, col*2)) = f2bf(hc[1][ntg][reg]);
                }
            }
        }
        __syncthreads();
        // ---- layer2: h += relu(h@Wb1+bb1) -> hC (final h) ----
        {
            bf16x8 a[2][4];
            #pragma unroll
            for (int rt = 0; rt < 2; ++rt)
                #pragma unroll
                for (int kk = 0; kk < 4; ++kk)
                    a[rt][kk] = *(const bf16x8*)(hB + swz(rt*16 + l15, kk*64 + l4*16));
            #pragma unroll
            for (int ntg = 0; ntg < 2; ++ntg) {
                f32x4 acc0 = {bbv[1][ntg],bbv[1][ntg],bbv[1][ntg],bbv[1][ntg]};
                f32x4 acc1 = acc0;
                #pragma unroll
                for (int kk = 0; kk < 4; ++kk) {
                    acc0 = __builtin_amdgcn_mfma_f32_16x16x32_bf16(a[0][kk], wfrag[1][ntg][kk], acc0, 0,0,0);
                    acc1 = __builtin_amdgcn_mfma_f32_16x16x32_bf16(a[1][kk], wfrag[1][ntg][kk], acc1, 0,0,0);
                }
                int col = colb + ntg*16 + l15;
                #pragma unroll
                for (int reg = 0; reg < 4; ++reg) {
                    float h0 = hc[0][ntg][reg] + fmaxf(acc0[reg], 0.f);
                    float h1 = hc[1][ntg][reg] + fmaxf(acc1[reg], 0.f);
                    *(u16*)(hC + swz(l4*4+reg,    col*2)) = f2bf(h0);
                    *(u16*)(hC + swz(16+l4*4+reg, col*2)) = f2bf(h1);
                }
            }
        }
        __syncthreads();
        // ---- epilogue: grad = h@Wo (+bo), scatter s*grad (waves 0,1) ----
        if (wid < 2) {
            bf16x8 a[4];
            #pragma unroll
            for (int kk = 0; kk < 4; ++kk)
                a[kk] = *(const bf16x8*)(hC + swz(wid*16 + l15, kk*64 + l4*16));
            f32x4 acc = {0.f,0.f,0.f,0.f};
            #pragma unroll
            for (int kk = 0; kk < 4; ++kk)
                acc = __builtin_amdgcn_mfma_f32_16x16x32_bf16(a[kk], wofrag[kk], acc, 0,0,0);
            if (l15 < 3) {
                int p = pt0 + wid*4 + l4;
                int b = p >> 14, n = p & (NPT-1);
                #pragma unroll
                for (int reg = 0; reg < 4; ++reg) {
                    int nb = n + reg - 2;
                    nb = nb < 0 ? 0 : (nb > NPT-1 ? NPT-1 : nb);
                    int pn = (b << 14) + nb;
                    atomicAdd(&dst[pn*3 + l15], s*(acc[reg] + bol));
                }
            }
        }
    }
}

extern "C" void kernel_launch(void* const* d_in, const int* in_sizes, int n_in,
                              void* d_out, int out_size, void* d_ws, size_t ws_size,
                              hipStream_t stream) {
    const float* pcl = (const float*)d_in[0];
    const float* Wf1 = (const float*)d_in[1];
    const float* bf1 = (const float*)d_in[2];
    const float* Wf2 = (const float*)d_in[3];
    const float* bf2 = (const float*)d_in[4];
    const float* W0  = (const float*)d_in[5];
    const float* b0  = (const float*)d_in[6];
    const float* Wb  = (const float*)d_in[7];
    const float* bb  = (const float*)d_in[8];
    const float* Wo  = (const float*)d_in[9];
    const float* bo  = (const float*)d_in[10];
    float* out = (float*)d_out;

    char* ws = (char*)d_ws;
    u16*   fproj = (u16*)ws;                              // TOTP*FD*2 = 8.4 MB
    float* bufA  = (float*)(ws + (size_t)TOTP*FD*2);
    float* bufB  = bufA + (size_t)TOTP*3;
    size_t pbytes = (size_t)TOTP*3*sizeof(float);

    fproj_mfma<<<512, 256, 0, stream>>>(pcl, Wf1, bf1, Wf2, bf2, W0, b0, fproj);

    float s = 0.2f;
    hipMemcpyAsync(bufA, pcl, pbytes, hipMemcpyDeviceToDevice, stream);
    step_mfma<<<768, 256, 0, stream>>>(pcl,  pcl, fproj, W0, Wb, bb, Wo, bo, bufA, s);
    s *= 0.95f;
    hipMemcpyAsync(bufB, bufA, pbytes, hipMemcpyDeviceToDevice, stream);
    step_mfma<<<768, 256, 0, stream>>>(bufA, pcl, fproj, W0, Wb, bb, Wo, bo, bufB, s);
    s *= 0.95f;
    hipMemcpyAsync(bufA, bufB, pbytes, hipMemcpyDeviceToDevice, stream);
    step_mfma<<<768, 256, 0, stream>>>(bufB, pcl, fproj, W0, Wb, bb, Wo, bo, bufA, s);
    s *= 0.95f;
    hipMemcpyAsync(out, bufA, pbytes, hipMemcpyDeviceToDevice, stream);
    step_mfma<<<768, 256, 0, stream>>>(bufA, pcl, fproj, W0, Wb, bb, Wo, bo, out, s);
}